// Round 5
// baseline (44.543 us; speedup 1.0000x reference)
//
#include <hip/hip_runtime.h>

// out[b,l,c,d] = p(c)*x0[d] + q(c)*x1[d]  (rank-2 outer product; x has L=2 so
// the 64-wide sliding window sees only taps s0=32-l, s1=33-l).
//   p(c) = x0[c]*F[s0,s0] + x1[c]*F[s1,s0]
//   q(c) = x0[c]*F[s0,s1] + x1[c]*F[s1,s1],  F = filt[0][l]
//
// Layouts (row-major flat):
//   x:    (32, 1024, 2)       -> x[(b*1024 + c)*2 + ch]
//   filt: (1, 2, 64, 64)      -> filt[(l*64 + s)*64 + t]
//   out:  (32, 2, 1024, 1024) -> out[((b*2 + l)*1024 + c)*1024 + d]
//
// Store-bound: 268.4 MB writes @ ~6-7 TB/s. Every store instruction is
// wave-contiguous (64 lanes x 16B = 1KB dense, line-aligned). ROWS=8 rows
// per block: 8 independent full-row stores per thread (MLP), 8192 blocks.
// R3 lesson kept: no nt stores with strided lanes; regular stores match the
// 7 TB/s fill-kernel path.

typedef __attribute__((ext_vector_type(4))) float f32x4;

#define ROWS 8

__global__ __launch_bounds__(256) void filter_rank2_kernel(
    const float* __restrict__ x, const float* __restrict__ filt,
    float* __restrict__ out) {
  const int B   = blockIdx.x;
  const int tid = threadIdx.x;
  const int rg  = B & 127;         // which group of ROWS rows within (b,l)
  const int l   = (B >> 7) & 1;
  const int b   = B >> 8;

  const int s0 = 32 - l, s1 = 33 - l;
  const float* F = filt + l * 4096;       // b,l block-uniform -> scalar loads
  const float a00 = F[s0 * 64 + s0];
  const float a01 = F[s0 * 64 + s1];
  const float a10 = F[s1 * 64 + s0];
  const float a11 = F[s1 * 64 + s1];

  const float* xb = x + (long long)b * 2048;   // (x0,x1) pairs along c
  const int c0 = rg * ROWS;

  float p[ROWS], q[ROWS];
#pragma unroll
  for (int i = 0; i < ROWS; i += 2) {
    const f32x4 xc = *(const f32x4*)(xb + 2 * (c0 + i));  // pairs c0+i, c0+i+1
    p[i]     = xc.x * a00 + xc.y * a10;
    q[i]     = xc.x * a01 + xc.y * a11;
    p[i + 1] = xc.z * a00 + xc.w * a10;
    q[i + 1] = xc.z * a01 + xc.w * a11;
  }

  const int d0 = tid * 4;                       // 4 d-values per thread
  const f32x4 t0 = *(const f32x4*)(xb + 2 * d0);      // pairs d0, d0+1
  const f32x4 t1 = *(const f32x4*)(xb + 2 * d0 + 4);  // pairs d0+2, d0+3

  float* ob = out + ((long long)(b * 2 + l) * 1024 + c0) * 1024 + d0;
#pragma unroll
  for (int i = 0; i < ROWS; ++i) {    // ROWS independent full-row stores
    f32x4 o;
    o.x = p[i] * t0.x + q[i] * t0.y;
    o.y = p[i] * t0.z + q[i] * t0.w;
    o.z = p[i] * t1.x + q[i] * t1.y;
    o.w = p[i] * t1.z + q[i] * t1.w;
    *(f32x4*)(ob + (long long)i * 1024) = o;   // full 4KB row per store instr
  }
}

extern "C" void kernel_launch(void* const* d_in, const int* in_sizes, int n_in,
                              void* d_out, int out_size, void* d_ws, size_t ws_size,
                              hipStream_t stream) {
  const float* x    = (const float*)d_in[0];
  const float* filt = (const float*)d_in[1];
  float* out        = (float*)d_out;

  // 32 b * 2 l * (1024/ROWS) row-groups = 8192 blocks
  const int blocks = 32 * 2 * (1024 / ROWS);
  filter_rank2_kernel<<<blocks, 256, 0, stream>>>(x, filt, out);
}